// Round 7
// baseline (100.512 us; speedup 1.0000x reference)
//
#include <hip/hip_runtime.h>

// Problem constants (fixed by reference setup_inputs).
#define BB   128
#define CC   1000
#define DD   512
#define CT   8              // classes per block tile
#define BSPL 8              // batches per block (register-prefetched in full)
#define NCT  (CC / CT)      // 125 c-tiles
#define NBCH (BB / BSPL)    // 16 b-chunks
#define NBLK (NCT * NBCH)   // 2000 blocks

#define POISON_U32 0xAAAAAAAAu   // harness poisons d_ws with 0xAA bytes

typedef float v2f __attribute__((ext_vector_type(2)));

// A&S 7.1.27 coefficients with 2^{-k/2} folded in, so that with
// inv = 1/(std+eps) and t = |w-mu|:
//   p = 1 + (A1*inv)t + ... + (A4*inv^4)t^4,  erfc(t*inv/sqrt(2)) ~= p^-4
// (|err| <= 5e-4 per element; loss-error bound ~0.26 << 2.15 threshold)
#define RS2 0.70710678118654752f
__device__ __constant__ const float A1 = 0.278393f * RS2;
__device__ __constant__ const float A2 = 0.230389f * RS2 * RS2;
__device__ __constant__ const float A3 = 0.000972f * RS2 * RS2 * RS2;
__device__ __constant__ const float A4 = 0.078108f * RS2 * RS2 * RS2 * RS2;

// Packed erfc-pair: 8 pk VALU + 2 trans-pipe rcp per PAIR of erfc evals.
__device__ __forceinline__ void erfc_pair_acc(v2f w, v2f m,
                                              v2f c1, v2f c2, v2f c3, v2f c4,
                                              v2f& acc) {
    v2f d = w - m;
    v2f t = __builtin_elementwise_max(d, -d);   // |d|; neg is a free VOP3P mod
    v2f p = c4 * t + c3;
    p = p * t + c2;
    p = p * t + c1;
    p = p * t + 1.0f;
    v2f r;
    r.x = __builtin_amdgcn_rcpf(p.x);
    r.y = __builtin_amdgcn_rcpf(p.y);
    v2f r2 = r * r;
    acc += r2 * r2;
}

// Per-batch folded coefficients from a std pair (amortized over CT classes).
__device__ __forceinline__ void make_coeffs(v2f s, v2f& c1, v2f& c2, v2f& c3,
                                            v2f& c4) {
    v2f se = s + 1e-8f;
    v2f inv;
    inv.x = __builtin_amdgcn_rcpf(se.x);
    inv.y = __builtin_amdgcn_rcpf(se.y);
    v2f inv2 = inv * inv;
    c1 = A1 * inv;
    c2 = A2 * inv2;
    c3 = A3 * (inv2 * inv);
    c4 = A4 * (inv2 * inv2);
}

// Single kernel: per-block tile sum -> partial store -> release counter;
// last block reduces all partials and writes the loss.  No f64 atomics.
__global__ __launch_bounds__(256) void erf_fused(
        const float* __restrict__ mu, const float* __restrict__ sd,
        const float* __restrict__ w, const int* __restrict__ label,
        float* __restrict__ partial, unsigned int* __restrict__ cnt,
        float* __restrict__ out) {
    const int ctile = blockIdx.x % NCT;
    const int bch   = blockIdx.x / NCT;
    const int c0    = ctile * CT;
    const int b0    = bch * BSPL;
    const int d0    = threadIdx.x * 2;

    // ---- issue every global load up front (independent, all in flight) ----
    v2f wv[CT], mv[BSPL], sv[BSPL];
    #pragma unroll
    for (int i = 0; i < CT; ++i)
        wv[i] = *(const v2f*)(w + (size_t)(c0 + i) * DD + d0);
    #pragma unroll
    for (int bi = 0; bi < BSPL; ++bi) {
        mv[bi] = *(const v2f*)(mu + (size_t)(b0 + bi) * DD + d0);
        sv[bi] = *(const v2f*)(sd + (size_t)(b0 + bi) * DD + d0);
    }

    const bool do_corr = (blockIdx.x < BB);
    v2f wl = (v2f)0.0f, ml = (v2f)0.0f, sl = (v2f)1.0f;
    if (do_corr) {
        const int b  = blockIdx.x;
        const int lb = label[b];
        wl = *(const v2f*)(w  + (size_t)lb * DD + d0);
        ml = *(const v2f*)(mu + (size_t)b  * DD + d0);
        sl = *(const v2f*)(sd + (size_t)b  * DD + d0);
    }

    // ---- pure-register compute: 64 packed erfc-pairs, no loads inside ----
    v2f acc0 = (v2f)0.0f, acc1 = (v2f)0.0f;
    #pragma unroll
    for (int bi = 0; bi < BSPL; ++bi) {
        v2f c1, c2, c3, c4;
        make_coeffs(sv[bi], c1, c2, c3, c4);
        #pragma unroll
        for (int i = 0; i < CT; i += 2) {
            erfc_pair_acc(wv[i],     mv[bi], c1, c2, c3, c4, acc0);
            erfc_pair_acc(wv[i + 1], mv[bi], c1, c2, c3, c4, acc1);
        }
    }
    if (do_corr) {
        v2f c1, c2, c3, c4;
        make_coeffs(sl, c1, c2, c3, c4);
        v2f corr = (v2f)0.0f;
        erfc_pair_acc(wl, ml, c1, c2, c3, c4, corr);
        acc0 -= 2.0f * corr;
    }

    // ---- block reduce ----
    v2f accv = acc0 + acc1;
    float v = accv.x + accv.y;
    #pragma unroll
    for (int off = 32; off > 0; off >>= 1)
        v += __shfl_down(v, off, 64);
    __shared__ float wsum[4];
    const int lane = threadIdx.x & 63;
    const int wave = threadIdx.x >> 6;
    if (lane == 0) wsum[wave] = v;
    __syncthreads();

    // ---- publish partial, detect last block (poison-aware counter) ----
    __shared__ int is_last;
    if (threadIdx.x == 0) {
        partial[blockIdx.x] = (wsum[0] + wsum[1]) + (wsum[2] + wsum[3]);
        // RELEASE orders the partial store before the counter bump, at agent
        // scope (cross-XCD visible).  One u32 atomic per block, relaxed data.
        unsigned int old = __hip_atomic_fetch_add(cnt, 1u, __ATOMIC_RELEASE,
                                                  __HIP_MEMORY_SCOPE_AGENT);
        is_last = (old == (unsigned)(NBLK - 1) ||
                   old == POISON_U32 + (unsigned)(NBLK - 1));
    }
    __syncthreads();

    // ---- last block: reduce all partials, write the loss ----
    if (is_last) {
        __threadfence();   // acquire side: invalidate stale L1/L2 lines
        double s = 0.0;
        for (int i = threadIdx.x; i < NBLK; i += 256)
            s += (double)partial[i];
        #pragma unroll
        for (int off = 32; off > 0; off >>= 1)
            s += __shfl_down(s, off, 64);
        __shared__ double dsum[4];
        if (lane == 0) dsum[wave] = s;
        __syncthreads();
        if (threadIdx.x == 0) {
            double total = (dsum[0] + dsum[1]) + (dsum[2] + dsum[3]);
            // loss = (2*B*D - 2*corr + T)/(B*C); partials carry T - 2*corr.
            out[0] = (float)((2.0 * BB * DD + total) / (double)(BB * CC));
        }
    }
}

extern "C" void kernel_launch(void* const* d_in, const int* in_sizes, int n_in,
                              void* d_out, int out_size, void* d_ws, size_t ws_size,
                              hipStream_t stream) {
    const float* mu    = (const float*)d_in[0];
    const float* sd    = (const float*)d_in[1];
    const float* w     = (const float*)d_in[2];
    const int*   label = (const int*)d_in[3];
    float* out = (float*)d_out;
    float* partial    = (float*)d_ws;                       // NBLK floats
    unsigned int* cnt = (unsigned int*)((char*)d_ws + NBLK * sizeof(float));

    erf_fused<<<dim3(NBLK), dim3(256), 0, stream>>>(mu, sd, w, label,
                                                    partial, cnt, out);
}

// Round 10
// 83.577 us; speedup vs baseline: 1.2026x; 1.2026x over previous
//
#include <hip/hip_runtime.h>

// Problem constants (fixed by reference setup_inputs).
#define BB   128
#define CC   1000
#define DD   512
#define CT   8              // classes per block tile
#define BSPL 8              // batches per block (register-prefetched in full)
#define NCT  (CC / CT)      // 125 c-tiles
#define NBCH (BB / BSPL)    // 16 b-chunks
#define NBLK (NCT * NBCH)   // 2000 blocks

typedef float v2f __attribute__((ext_vector_type(2)));
typedef int   v2i __attribute__((ext_vector_type(2)));

// A&S 7.1.27 coefficients with 2^{-k/2} folded in, so that with
// inv = 1/(std+eps) and t = |w-mu|:
//   p = 1 + (A1*inv)t + ... + (A4*inv^4)t^4,  erfc(t*inv/sqrt(2)) ~= p^-4
// (|err| <= 5e-4/element; loss-error bound ~0.26 << 2.15 threshold)
// Identical numerics to the round-6 kernel that passed with absmax 0.0.
#define RS2 0.70710678118654752f
__device__ __constant__ const float A1 = 0.278393f * RS2;
__device__ __constant__ const float A2 = 0.230389f * RS2 * RS2;
__device__ __constant__ const float A3 = 0.000972f * RS2 * RS2 * RS2;
__device__ __constant__ const float A4 = 0.078108f * RS2 * RS2 * RS2 * RS2;

// 1/p for p >= 1 with NO transcendental-pipe op: integer magic seed
// (rel err ~3.4%) + 2 Newton steps -> rel err ~1.3e-6 (r^4 err ~5e-6).
// Pure VALU; frees the quarter-rate trans pipe (R7 counters: ~45% of body
// time unaccounted by VALUBusy — the serialized v_rcp stream).
// Corners: p<=~1e35 keeps the seed normal; r^4 underflow flushes to 0
// exactly where erfc -> 0.
__device__ __forceinline__ v2f fast_rcp(v2f p) {
    v2i i = __builtin_bit_cast(v2i, p);
    i = (v2i)(0x7EF311C3) - i;
    v2f r = __builtin_bit_cast(v2f, i);
    r = r * ((v2f)2.0f - p * r);
    r = r * ((v2f)2.0f - p * r);
    return r;
}

// erfc-pair: sub, 2x |.|, 4 FMA Horner, magic-rcp (10 VALU), square-square.
__device__ __forceinline__ void erfc_pair_acc(v2f w, v2f m,
                                              v2f c1, v2f c2, v2f c3, v2f c4,
                                              v2f& acc) {
    v2f d = w - m;
    v2f t = __builtin_elementwise_max(d, -d);   // |d|
    v2f p = c4 * t + c3;
    p = p * t + c2;
    p = p * t + c1;
    p = p * t + 1.0f;
    v2f r  = fast_rcp(p);
    v2f r2 = r * r;
    acc += r2 * r2;
}

// Per-batch folded coefficients from a std pair (9 calls/thread; the 18
// v_rcp here are negligible).
__device__ __forceinline__ void make_coeffs(v2f s, v2f& c1, v2f& c2, v2f& c3,
                                            v2f& c4) {
    v2f se = s + 1e-8f;
    v2f inv;
    inv.x = __builtin_amdgcn_rcpf(se.x);
    inv.y = __builtin_amdgcn_rcpf(se.y);
    v2f inv2 = inv * inv;
    c1 = A1 * inv;
    c2 = A2 * inv2;
    c3 = A3 * (inv2 * inv);
    c4 = A4 * (inv2 * inv2);
}

// partial[blk] = block tile sum of erfc(y); blocks 0..BB-1 also fold in
// -2*corr_b.  Plain stores, NO end-of-block atomics (R7: 2000 same-line
// atomics cost +20 us).  Thread owns d = {2t, 2t+1}.
__global__ __launch_bounds__(256) void erf_main(
        const float* __restrict__ mu, const float* __restrict__ sd,
        const float* __restrict__ w, const int* __restrict__ label,
        float* __restrict__ partial) {
    const int ctile = blockIdx.x % NCT;
    const int bch   = blockIdx.x / NCT;
    const int c0    = ctile * CT;
    const int b0    = bch * BSPL;
    const int d0    = threadIdx.x * 2;

    // ---- issue every global load up front (independent, all in flight) ----
    v2f wv[CT], mv[BSPL], sv[BSPL];
    #pragma unroll
    for (int i = 0; i < CT; ++i)
        wv[i] = *(const v2f*)(w + (size_t)(c0 + i) * DD + d0);
    #pragma unroll
    for (int bi = 0; bi < BSPL; ++bi) {
        mv[bi] = *(const v2f*)(mu + (size_t)(b0 + bi) * DD + d0);
        sv[bi] = *(const v2f*)(sd + (size_t)(b0 + bi) * DD + d0);
    }

    const bool do_corr = (blockIdx.x < BB);
    v2f wl = (v2f)0.0f, ml = (v2f)0.0f, sl = (v2f)1.0f;
    if (do_corr) {
        const int b  = blockIdx.x;
        const int lb = label[b];
        wl = *(const v2f*)(w  + (size_t)lb * DD + d0);
        ml = *(const v2f*)(mu + (size_t)b  * DD + d0);
        sl = *(const v2f*)(sd + (size_t)b  * DD + d0);
    }

    // ---- pure-register compute: 64 erfc-pairs, no loads, no trans ops ----
    v2f acc0 = (v2f)0.0f, acc1 = (v2f)0.0f;
    #pragma unroll
    for (int bi = 0; bi < BSPL; ++bi) {
        v2f c1, c2, c3, c4;
        make_coeffs(sv[bi], c1, c2, c3, c4);
        #pragma unroll
        for (int i = 0; i < CT; i += 2) {
            erfc_pair_acc(wv[i],     mv[bi], c1, c2, c3, c4, acc0);
            erfc_pair_acc(wv[i + 1], mv[bi], c1, c2, c3, c4, acc1);
        }
    }
    if (do_corr) {
        v2f c1, c2, c3, c4;
        make_coeffs(sl, c1, c2, c3, c4);
        v2f corr = (v2f)0.0f;
        erfc_pair_acc(wl, ml, c1, c2, c3, c4, corr);
        acc0 -= 2.0f * corr;
    }

    // ---- block reduce, one plain store ----
    v2f accv = acc0 + acc1;
    float v = accv.x + accv.y;
    #pragma unroll
    for (int off = 32; off > 0; off >>= 1)
        v += __shfl_down(v, off, 64);
    __shared__ float wsum[4];
    const int lane = threadIdx.x & 63;
    const int wave = threadIdx.x >> 6;
    if (lane == 0) wsum[wave] = v;
    __syncthreads();
    if (threadIdx.x == 0)
        partial[blockIdx.x] = (wsum[0] + wsum[1]) + (wsum[2] + wsum[3]);
}

// loss = (2*B*D + sum(partial)) / (B*C)   [partials already carry -2*corr]
__global__ __launch_bounds__(256) void finalize_kernel(
        const float* __restrict__ partial, float* __restrict__ out) {
    double s = 0.0;
    for (int i = threadIdx.x; i < NBLK; i += 256)
        s += (double)partial[i];
    #pragma unroll
    for (int off = 32; off > 0; off >>= 1)
        s += __shfl_down(s, off, 64);
    __shared__ double dsum[4];
    const int lane = threadIdx.x & 63;
    const int wave = threadIdx.x >> 6;
    if (lane == 0) dsum[wave] = s;
    __syncthreads();
    if (threadIdx.x == 0) {
        double total = (dsum[0] + dsum[1]) + (dsum[2] + dsum[3]);
        out[0] = (float)((2.0 * BB * DD + total) / (double)(BB * CC));
    }
}

extern "C" void kernel_launch(void* const* d_in, const int* in_sizes, int n_in,
                              void* d_out, int out_size, void* d_ws, size_t ws_size,
                              hipStream_t stream) {
    const float* mu    = (const float*)d_in[0];
    const float* sd    = (const float*)d_in[1];
    const float* w     = (const float*)d_in[2];
    const int*   label = (const int*)d_in[3];
    float* out     = (float*)d_out;
    float* partial = (float*)d_ws;   // NBLK floats, fully rewritten every call

    erf_main<<<dim3(NBLK), dim3(256), 0, stream>>>(mu, sd, w, label, partial);
    finalize_kernel<<<dim3(1), dim3(256), 0, stream>>>(partial, out);
}

// Round 11
// 77.291 us; speedup vs baseline: 1.3004x; 1.0813x over previous
//
#include <hip/hip_runtime.h>

// Problem constants (fixed by reference setup_inputs).
#define BB   128
#define CC   1000
#define DD   512
#define CT   8              // classes per block tile
#define BSPL 8              // batches per block (register-prefetched in full)
#define NCT  (CC / CT)      // 125 c-tiles
#define NBCH (BB / BSPL)    // 16 b-chunks
#define NBLK (NCT * NBCH)   // 2000 blocks

typedef float v2f __attribute__((ext_vector_type(2)));

// Exponential erfc fit:  erfc(x) ~= exp(-(C1 x + C2 x^2)),  x >= 0
// (|err| <= 2e-3/element, sign-mixed; loss-error bound ~0.3 << 2.15).
// With x = t*inv/sqrt(2), t = |w-mu|, inv = 1/(std+1e-8), and folding
// log2(e) so we can use hardware v_exp_f32 (exp2):
//   erfc = exp2( -(KE1*inv)*t - (KE2*inv^2)*t^2 )
// Per element: v_sub + v_fma(|.| mod) + v_mul(|.| mod) + v_exp + v_add
//            = 4 VALU + 1 trans  (R6 was 8 VALU + 1 trans; R10 proved the
//              trans pipe overlaps for free and VALU issue is the bound).
#define KE1 (1.09500814703333f * 1.44269504088896f * 0.70710678118655f)
#define KE2 (0.75651138383854f * 1.44269504088896f * 0.5f)

// One erfc element; ne1 = -KE1*inv, ne2 = -KE2*inv^2 (both <= 0).
// fabsf folds into VOP3 |.| input modifiers -> no explicit abs instruction.
__device__ __forceinline__ float erfc_e(float d, float ne1, float ne2) {
    float t = __builtin_fabsf(d);
    float a = t * __builtin_fmaf(ne2, t, ne1);   // a <= 0 always; no NaN/inf-arg corner
    return __builtin_amdgcn_exp2f(a);            // v_exp_f32
}

// Per-batch folded coefficients from a std pair (9 calls/thread, negligible).
__device__ __forceinline__ void make_coeffs(v2f s, v2f& ne1, v2f& ne2) {
    v2f se = s + 1e-8f;
    v2f inv;
    inv.x = __builtin_amdgcn_rcpf(se.x);
    inv.y = __builtin_amdgcn_rcpf(se.y);
    ne1 = (v2f)(-KE1) * inv;
    ne2 = (v2f)(-KE2) * (inv * inv);
}

// partial[blk] = block tile sum of erfc(y); blocks 0..BB-1 also fold in
// -2*corr_b.  Plain stores, NO end-of-block atomics (R7: 2000 same-line
// atomics cost +20 us).  Thread owns d = {2t, 2t+1}.
__global__ __launch_bounds__(256) void erf_main(
        const float* __restrict__ mu, const float* __restrict__ sd,
        const float* __restrict__ w, const int* __restrict__ label,
        float* __restrict__ partial) {
    const int ctile = blockIdx.x % NCT;
    const int bch   = blockIdx.x / NCT;
    const int c0    = ctile * CT;
    const int b0    = bch * BSPL;
    const int d0    = threadIdx.x * 2;

    // ---- issue every global load up front (independent, all in flight) ----
    v2f wv[CT], mv[BSPL], sv[BSPL];
    #pragma unroll
    for (int i = 0; i < CT; ++i)
        wv[i] = *(const v2f*)(w + (size_t)(c0 + i) * DD + d0);
    #pragma unroll
    for (int bi = 0; bi < BSPL; ++bi) {
        mv[bi] = *(const v2f*)(mu + (size_t)(b0 + bi) * DD + d0);
        sv[bi] = *(const v2f*)(sd + (size_t)(b0 + bi) * DD + d0);
    }

    const bool do_corr = (blockIdx.x < BB);
    v2f wl = (v2f)0.0f, ml = (v2f)0.0f, sl = (v2f)1.0f;
    if (do_corr) {
        const int b  = blockIdx.x;
        const int lb = label[b];
        wl = *(const v2f*)(w  + (size_t)lb * DD + d0);
        ml = *(const v2f*)(mu + (size_t)b  * DD + d0);
        sl = *(const v2f*)(sd + (size_t)b  * DD + d0);
    }

    // ---- pure-register compute: 128 erfc elements, no loads inside ----
    // 4 independent accumulators to keep the v_add chains off the critical path.
    float a0 = 0.0f, a1 = 0.0f, a2 = 0.0f, a3 = 0.0f;
    #pragma unroll
    for (int bi = 0; bi < BSPL; ++bi) {
        v2f ne1, ne2;
        make_coeffs(sv[bi], ne1, ne2);
        const float mx = mv[bi].x, my = mv[bi].y;
        #pragma unroll
        for (int i = 0; i < CT; i += 2) {
            a0 += erfc_e(wv[i].x     - mx, ne1.x, ne2.x);
            a1 += erfc_e(wv[i].y     - my, ne1.y, ne2.y);
            a2 += erfc_e(wv[i + 1].x - mx, ne1.x, ne2.x);
            a3 += erfc_e(wv[i + 1].y - my, ne1.y, ne2.y);
        }
    }
    if (do_corr) {
        v2f ne1, ne2;
        make_coeffs(sl, ne1, ne2);
        a0 -= 2.0f * erfc_e(wl.x - ml.x, ne1.x, ne2.x);
        a1 -= 2.0f * erfc_e(wl.y - ml.y, ne1.y, ne2.y);
    }

    // ---- block reduce, one plain store ----
    float v = (a0 + a1) + (a2 + a3);
    #pragma unroll
    for (int off = 32; off > 0; off >>= 1)
        v += __shfl_down(v, off, 64);
    __shared__ float wsum[4];
    const int lane = threadIdx.x & 63;
    const int wave = threadIdx.x >> 6;
    if (lane == 0) wsum[wave] = v;
    __syncthreads();
    if (threadIdx.x == 0)
        partial[blockIdx.x] = (wsum[0] + wsum[1]) + (wsum[2] + wsum[3]);
}

// loss = (2*B*D + sum(partial)) / (B*C)   [partials already carry -2*corr]
__global__ __launch_bounds__(256) void finalize_kernel(
        const float* __restrict__ partial, float* __restrict__ out) {
    double s = 0.0;
    for (int i = threadIdx.x; i < NBLK; i += 256)
        s += (double)partial[i];
    #pragma unroll
    for (int off = 32; off > 0; off >>= 1)
        s += __shfl_down(s, off, 64);
    __shared__ double dsum[4];
    const int lane = threadIdx.x & 63;
    const int wave = threadIdx.x >> 6;
    if (lane == 0) dsum[wave] = s;
    __syncthreads();
    if (threadIdx.x == 0) {
        double total = (dsum[0] + dsum[1]) + (dsum[2] + dsum[3]);
        out[0] = (float)((2.0 * BB * DD + total) / (double)(BB * CC));
    }
}

extern "C" void kernel_launch(void* const* d_in, const int* in_sizes, int n_in,
                              void* d_out, int out_size, void* d_ws, size_t ws_size,
                              hipStream_t stream) {
    const float* mu    = (const float*)d_in[0];
    const float* sd    = (const float*)d_in[1];
    const float* w     = (const float*)d_in[2];
    const int*   label = (const int*)d_in[3];
    float* out     = (float*)d_out;
    float* partial = (float*)d_ws;   // NBLK floats, fully rewritten every call

    erf_main<<<dim3(NBLK), dim3(256), 0, stream>>>(mu, sd, w, label, partial);
    finalize_kernel<<<dim3(1), dim3(256), 0, stream>>>(partial, out);
}